// Round 7
// baseline (204.055 us; speedup 1.0000x reference)
//
#include <hip/hip_runtime.h>

// Problem constants (from reference)
#define NUM_TOKENS   16384
#define NUM_HEADS    8
#define HEAD_SIZE    128
#define NUM_BLOCKS   4096
#define BLOCK_SIZE_  16
#define SLOT_ELEMS   (NUM_HEADS * HEAD_SIZE)          // 1024 floats per slot
#define SLOT_VEC4    (SLOT_ELEMS / 4)                 // 256 float4 per slot
#define NUM_SLOTS    (NUM_BLOCKS * BLOCK_SIZE_)       // 65536
#define CACHE_ELEMS  ((long)NUM_SLOTS * SLOT_ELEMS)   // 67,108,864 floats per cache

// Non-temporal 16B load/store helpers (streaming data, zero reuse).
typedef float f4_t __attribute__((ext_vector_type(4)));
__device__ __forceinline__ void nt_store(float4* p, float4 v) {
    __builtin_nontemporal_store(*(f4_t*)&v, (f4_t*)p);
}
__device__ __forceinline__ float4 nt_load(const float4* p) {
    f4_t v = __builtin_nontemporal_load((const f4_t*)p);
    return *(float4*)&v;
}

// Kernel A: token scatter + inverse-map build fused.
// One block per token: thread moves one float4 of K and one of V (contiguous
// 4KB runs per cache at the destination slot). Lane 0 also records
// inv[slot] = token so the hole-copy kernel can skip this slot. Slots are
// unique -> race-free. inv must be pre-filled with -1 (memset 0xFF) before
// this kernel runs; copy_holes runs after (kernel boundary = ordering).
__global__ __launch_bounds__(256)
void scatter_build_kernel(const float4* __restrict__ key,
                          const float4* __restrict__ value,
                          const int* __restrict__ slot_mapping,
                          int* __restrict__ inv,
                          float4* __restrict__ ok,
                          float4* __restrict__ ov) {
    int token = blockIdx.x;
    int slot = slot_mapping[token];   // one broadcast transaction per block
    if (slot < 0) return;             // dropped token: leave hole as -1
    if (threadIdx.x == 0) inv[slot] = token;
    int tid = threadIdx.x;            // 0..255
    long src = (long)token * SLOT_VEC4 + tid;
    long dst = (long)slot  * SLOT_VEC4 + tid;
    float4 rk = nt_load(key + src);
    float4 rv = nt_load(value + src);
    nt_store(ok + dst, rk);
    nt_store(ov + dst, rv);
}

// Kernel B: copy the holes, 4 consecutive slots per block. One aligned int4
// load fetches the 4 inv entries; each non-overwritten slot is a pure
// streaming 4KB copy from each input cache (block-uniform branch per slot).
__global__ __launch_bounds__(256)
void copy_holes4_kernel(const float4* __restrict__ kc,
                        const float4* __restrict__ vc,
                        const int4* __restrict__ inv4,
                        float4* __restrict__ ok,
                        float4* __restrict__ ov) {
    int s0 = blockIdx.x * 4;                       // first of 4 slots
    int4 iv = inv4[blockIdx.x];                    // 4 inv entries, one load
    int tid = threadIdx.x;
    long base = (long)s0 * SLOT_VEC4 + tid;
#pragma unroll
    for (int j = 0; j < 4; ++j) {
        int tok = (j == 0) ? iv.x : (j == 1) ? iv.y : (j == 2) ? iv.z : iv.w;
        if (tok < 0) {                             // hole: copy old cache
            long i = base + (long)j * SLOT_VEC4;
            float4 rk = nt_load(kc + i);
            float4 rv = nt_load(vc + i);
            nt_store(ok + i, rk);
            nt_store(ov + i, rv);
        }
    }
}

// --- Fallback two-pass path (if ws too small) -------------------------------

__global__ void copy_cache_kernel(const float4* __restrict__ kc,
                                  const float4* __restrict__ vc,
                                  float4* __restrict__ ok,
                                  float4* __restrict__ ov,
                                  long n4) {
    long i = (long)blockIdx.x * blockDim.x + threadIdx.x;
    long stride = (long)gridDim.x * blockDim.x;
    for (; i < n4; i += stride) {
        ok[i] = kc[i];
        ov[i] = vc[i];
    }
}

__global__ void scatter_kv_kernel(const float4* __restrict__ key,
                                  const float4* __restrict__ value,
                                  const int* __restrict__ slot_mapping,
                                  float4* __restrict__ ok,
                                  float4* __restrict__ ov) {
    int token = blockIdx.x;
    int slot = slot_mapping[token];
    if (slot < 0) return;
    int tid = threadIdx.x;
    long src = (long)token * SLOT_VEC4 + tid;
    long dst = (long)slot  * SLOT_VEC4 + tid;
    ok[dst] = key[src];
    ov[dst] = value[src];
}

extern "C" void kernel_launch(void* const* d_in, const int* in_sizes, int n_in,
                              void* d_out, int out_size, void* d_ws, size_t ws_size,
                              hipStream_t stream) {
    const float* key   = (const float*)d_in[0];
    const float* value = (const float*)d_in[1];
    const float* kc    = (const float*)d_in[2];
    const float* vc    = (const float*)d_in[3];
    const int*   slots = (const int*)d_in[4];   // int32 on device (harness contract)
    // d_in[5], d_in[6] = k_scale, v_scale — unused (kv_cache_dtype='auto')

    float* ok = (float*)d_out;
    float* ov = ok + CACHE_ELEMS;

    if (ws_size >= (size_t)NUM_SLOTS * sizeof(int)) {
        int* inv = (int*)d_ws;
        hipMemsetAsync(inv, 0xFF, NUM_SLOTS * sizeof(int), stream);
        scatter_build_kernel<<<NUM_TOKENS, 256, 0, stream>>>(
            (const float4*)key, (const float4*)value, slots, inv,
            (float4*)ok, (float4*)ov);
        copy_holes4_kernel<<<NUM_SLOTS / 4, 256, 0, stream>>>(
            (const float4*)kc, (const float4*)vc, (const int4*)inv,
            (float4*)ok, (float4*)ov);
    } else {
        long n4 = CACHE_ELEMS / 4;
        copy_cache_kernel<<<2048, 256, 0, stream>>>(
            (const float4*)kc, (const float4*)vc, (float4*)ok, (float4*)ov, n4);
        scatter_kv_kernel<<<NUM_TOKENS, 256, 0, stream>>>(
            (const float4*)key, (const float4*)value, slots, (float4*)ok, (float4*)ov);
    }
}

// Round 8
// 202.111 us; speedup vs baseline: 1.0096x; 1.0096x over previous
//
#include <hip/hip_runtime.h>

// Problem constants (from reference)
#define NUM_TOKENS   16384
#define NUM_HEADS    8
#define HEAD_SIZE    128
#define NUM_BLOCKS   4096
#define BLOCK_SIZE_  16
#define SLOT_ELEMS   (NUM_HEADS * HEAD_SIZE)          // 1024 floats per slot
#define SLOT_VEC4    (SLOT_ELEMS / 4)                 // 256 float4 per slot
#define NUM_SLOTS    (NUM_BLOCKS * BLOCK_SIZE_)       // 65536
#define CACHE_ELEMS  ((long)NUM_SLOTS * SLOT_ELEMS)   // 67,108,864 floats per cache

// Non-temporal 16B load/store helpers (streaming data, zero reuse — bypass L2
// churn). clang builtins need ext_vector_type, not HIP's float4 struct.
typedef float f4_t __attribute__((ext_vector_type(4)));
__device__ __forceinline__ void nt_store(float4* p, float4 v) {
    __builtin_nontemporal_store(*(f4_t*)&v, (f4_t*)p);
}
__device__ __forceinline__ float4 nt_load(const float4* p) {
    f4_t v = __builtin_nontemporal_load((const f4_t*)p);
    return *(float4*)&v;
}

// inv[slot] = token index writing that slot, or -1. Slots are unique, so the
// scatter is race-free. (inv is pre-filled with -1 via hipMemsetAsync 0xFF.)
__global__ void build_inverse_kernel(const int* __restrict__ slot_mapping,
                                     int* __restrict__ inv) {
    int t = blockIdx.x * blockDim.x + threadIdx.x;
    if (t < NUM_TOKENS) {
        int s = slot_mapping[t];
        if (s >= 0) inv[s] = t;
    }
}

// Kernel A: token scatter. One block per token; thread moves one float4 of K
// and one of V. Sequential token reads, contiguous-4KB scattered writes.
__global__ __launch_bounds__(256)
void scatter_kv_kernel(const float4* __restrict__ key,
                       const float4* __restrict__ value,
                       const int* __restrict__ slot_mapping,
                       float4* __restrict__ ok,
                       float4* __restrict__ ov) {
    int token = blockIdx.x;
    int slot = slot_mapping[token];   // one broadcast transaction per block
    if (slot < 0) return;             // dropped token
    int tid = threadIdx.x;            // 0..255
    long src = (long)token * SLOT_VEC4 + tid;
    long dst = (long)slot  * SLOT_VEC4 + tid;
    float4 rk = nt_load(key + src);
    float4 rv = nt_load(value + src);
    nt_store(ok + dst, rk);
    nt_store(ov + dst, rv);
}

// Kernel B: copy the holes. One block per slot; wave-uniform early exit if
// the slot is overwritten by a token (kernel A handles it). Otherwise pure
// streaming copy of 4KB from each input cache to the output. Dense moving
// window across the whole cache (blocks dispatch roughly in order).
__global__ __launch_bounds__(256)
void copy_holes_kernel(const float4* __restrict__ kc,
                       const float4* __restrict__ vc,
                       const int* __restrict__ inv,
                       float4* __restrict__ ok,
                       float4* __restrict__ ov) {
    int slot = blockIdx.x;
    if (inv[slot] >= 0) return;       // overwritten: scatter kernel owns it
    long i = (long)slot * SLOT_VEC4 + threadIdx.x;
    float4 rk = nt_load(kc + i);
    float4 rv = nt_load(vc + i);
    nt_store(ok + i, rk);
    nt_store(ov + i, rv);
}

// --- Fallback two-pass path (if ws too small) -------------------------------

__global__ void copy_cache_kernel(const float4* __restrict__ kc,
                                  const float4* __restrict__ vc,
                                  float4* __restrict__ ok,
                                  float4* __restrict__ ov,
                                  long n4) {
    long i = (long)blockIdx.x * blockDim.x + threadIdx.x;
    long stride = (long)gridDim.x * blockDim.x;
    for (; i < n4; i += stride) {
        ok[i] = kc[i];
        ov[i] = vc[i];
    }
}

extern "C" void kernel_launch(void* const* d_in, const int* in_sizes, int n_in,
                              void* d_out, int out_size, void* d_ws, size_t ws_size,
                              hipStream_t stream) {
    const float* key   = (const float*)d_in[0];
    const float* value = (const float*)d_in[1];
    const float* kc    = (const float*)d_in[2];
    const float* vc    = (const float*)d_in[3];
    const int*   slots = (const int*)d_in[4];   // int32 on device (harness contract)
    // d_in[5], d_in[6] = k_scale, v_scale — unused (kv_cache_dtype='auto')

    float* ok = (float*)d_out;
    float* ov = ok + CACHE_ELEMS;

    if (ws_size >= (size_t)NUM_SLOTS * sizeof(int)) {
        int* inv = (int*)d_ws;
        hipMemsetAsync(inv, 0xFF, NUM_SLOTS * sizeof(int), stream);
        build_inverse_kernel<<<(NUM_TOKENS + 255) / 256, 256, 0, stream>>>(slots, inv);
        copy_holes_kernel<<<NUM_SLOTS, 256, 0, stream>>>(
            (const float4*)kc, (const float4*)vc, inv, (float4*)ok, (float4*)ov);
        scatter_kv_kernel<<<NUM_TOKENS, 256, 0, stream>>>(
            (const float4*)key, (const float4*)value, slots, (float4*)ok, (float4*)ov);
    } else {
        long n4 = CACHE_ELEMS / 4;
        copy_cache_kernel<<<2048, 256, 0, stream>>>(
            (const float4*)kc, (const float4*)vc, (float4*)ok, (float4*)ov, n4);
        scatter_kv_kernel<<<NUM_TOKENS, 256, 0, stream>>>(
            (const float4*)key, (const float4*)value, slots, (float4*)ok, (float4*)ov);
    }
}